// Round 2
// baseline (7998.657 us; speedup 1.0000x reference)
//
#include <hip/hip_runtime.h>
#include <hip/hip_bf16.h>

using bf = __hip_bfloat16;

// Model dims
#define V_   32000
#define DM   1024
#define LQ   1024
#define BB   4
#define NLAY 2
#define NE   8
#define HH   1024
#define DS   16
#define DC   4
#define DI   2048
#define DTR  64
#define NTOK (BB*LQ)   // 4096

__device__ inline float tofl(float x) { return x; }
__device__ inline float tofl(bf x) { return __bfloat162float(x); }

// ---------------------------------------------------------------------------
// Generic tiled GEMM: C[M,N] = epi(A[M,K] @ B[N,K]^T + bias), f32 accumulate.
// A dtype templated (float or bf16 intermediates); B/bias are f32 weights;
// C is bf16 intermediate. Optional expert mode (cnt/offs non-null, grid.z=e):
//   permmode&1: gather A rows through perm;  permmode&2: scatter C rows
//   through perm and scale by scale[token].
// ---------------------------------------------------------------------------
#define TM 64
#define TN 64
#define TKK 16

template<typename TA>
__global__ __launch_bounds__(256) void gemm_nt(
    const TA* __restrict__ A, int lda,
    const float* __restrict__ Bw, int ldb,
    bf* __restrict__ C, int ldc,
    int M, int N, int K,
    const float* __restrict__ bias, int epi,        // 0 none, 1 softplus, 2 relu
    const int* __restrict__ cnt, const int* __restrict__ offs,
    const int* __restrict__ perm, int permmode,
    const float* __restrict__ scale,
    long long strideB_e, long long stride_bias_e)
{
    int e = blockIdx.z;
    int Meff = M;
    int rowoff = 0;
    if (cnt) {
        Meff = cnt[e];
        rowoff = offs[e];
        Bw += (long long)e * strideB_e;
        if (bias) bias += (long long)e * stride_bias_e;
    }
    int m0 = blockIdx.y * TM;
    if (m0 >= Meff) return;
    int n0 = blockIdx.x * TN;

    __shared__ float As[TKK][TM];
    __shared__ float Bs[TKK][TN];

    int tid = threadIdx.x;
    int tx = tid & 15, ty = tid >> 4;
    float acc[4][4] = {};

    for (int k0 = 0; k0 < K; k0 += TKK) {
        for (int i = tid; i < TM * TKK; i += 256) {
            int r = i / TKK, c = i % TKK;
            int m = m0 + r;
            float v = 0.f;
            if (m < Meff) {
                int ar = rowoff + m;
                int arow = (permmode & 1) ? perm[ar] : ar;
                v = tofl(A[(long long)arow * lda + k0 + c]);
            }
            As[c][r] = v;
        }
        for (int i = tid; i < TN * TKK; i += 256) {
            int r = i / TKK, c = i % TKK;
            int n = n0 + r;
            float v = 0.f;
            if (n < N) v = Bw[(long long)n * ldb + k0 + c];
            Bs[c][r] = v;
        }
        __syncthreads();
#pragma unroll
        for (int kk = 0; kk < TKK; ++kk) {
            float a[4], b[4];
#pragma unroll
            for (int i = 0; i < 4; i++) a[i] = As[kk][ty * 4 + i];
#pragma unroll
            for (int j = 0; j < 4; j++) b[j] = Bs[kk][tx * 4 + j];
#pragma unroll
            for (int i = 0; i < 4; i++)
#pragma unroll
                for (int j = 0; j < 4; j++) acc[i][j] += a[i] * b[j];
        }
        __syncthreads();
    }

#pragma unroll
    for (int i = 0; i < 4; i++) {
        int m = m0 + ty * 4 + i;
        if (m >= Meff) continue;
        long long crow;
        float sc = 1.f;
        int ar = rowoff + m;
        if (permmode & 2) { int tok = perm[ar]; crow = tok; sc = scale[tok]; }
        else crow = ar;
#pragma unroll
        for (int j = 0; j < 4; j++) {
            int n = n0 + tx * 4 + j;
            if (n >= N) continue;
            float v = acc[i][j];
            if (bias) v += bias[n];
            if (epi == 1) v = (v > 20.f) ? v : log1pf(__expf(v));
            else if (epi == 2) v = fmaxf(v, 0.f);
            v *= sc;
            C[crow * ldc + n] = __float2bfloat16(v);
        }
    }
}

// ---------------------------------------------------------------------------
__global__ __launch_bounds__(256) void embed_kernel(
    const int* __restrict__ tokens, const float* __restrict__ emb,
    const float* __restrict__ pos, float* __restrict__ X)
{
    int id = blockIdx.x * 256 + threadIdx.x;   // NTOK*DM threads
    int r = id >> 10, d = id & 1023;
    int l = r & (LQ - 1);
    int tok = tokens[r];
    X[id] = emb[(size_t)tok * DM + d] + pos[l * DM + d];
}

// causal depthwise conv (DC=4) + SiLU.  u lives in XZ[:, 0:DI], row stride 2*DI
__global__ __launch_bounds__(256) void conv_kernel(
    const bf* __restrict__ XZ, const float* __restrict__ cw,
    const float* __restrict__ cb, bf* __restrict__ UC)
{
    int id = blockIdx.x * 256 + threadIdx.x;   // NTOK*DI threads
    int d = id & (DI - 1);
    int r = id >> 11;
    int l = r & (LQ - 1);
    float acc = cb[d];
#pragma unroll
    for (int j = 0; j < DC; j++) {
        int ll = l - (DC - 1) + j;
        if (ll >= 0)
            acc += tofl(XZ[(size_t)(r - (DC - 1) + j) * (2 * DI) + d]) * cw[d * DC + j];
    }
    float sg = 1.f / (1.f + __expf(-acc));
    UC[id] = __float2bfloat16(acc * sg);
}

// SSM scan: one thread per (b,d), h[DS] in registers; fuses +u*D and *silu(z);
// writes gated output in-place over DT (read-before-write by same thread).
__global__ __launch_bounds__(256) void scan_kernel(
    const bf* __restrict__ UC, bf* __restrict__ DT,
    const bf* __restrict__ W96, const bf* __restrict__ XZ,
    const float* __restrict__ A_log, const float* __restrict__ D_ssm)
{
    int tid = blockIdx.x * 256 + threadIdx.x;   // BB*DI threads
    int d = tid & (DI - 1);
    int b = tid >> 11;
    float A[DS];
#pragma unroll
    for (int n = 0; n < DS; n++) A[n] = -__expf(A_log[d * DS + n]);
    float Dv = D_ssm[d];
    float h[DS];
#pragma unroll
    for (int n = 0; n < DS; n++) h[n] = 0.f;

    for (int l = 0; l < LQ; l++) {
        int r = (b << 10) + l;
        float u = tofl(UC[(size_t)r * DI + d]);
        float dt = tofl(DT[(size_t)r * DI + d]);
        float du = dt * u;
        float y = 0.f;
#pragma unroll
        for (int n = 0; n < DS; n++) {
            float Bv = tofl(W96[r * 96 + DTR + n]);
            float Cv = tofl(W96[r * 96 + DTR + DS + n]);
            h[n] = __expf(dt * A[n]) * h[n] + du * Bv;
            y += h[n] * Cv;
        }
        float z = tofl(XZ[(size_t)r * (2 * DI) + DI + d]);
        float sil = z / (1.f + __expf(-z));
        DT[(size_t)r * DI + d] = __float2bfloat16((y + u * Dv) * sil);
    }
}

// LN(src) * g + b added into f32 residual stream X.  One block per row.
__global__ __launch_bounds__(256) void ln_residual_kernel(
    float* __restrict__ X, const bf* __restrict__ src,
    const float* __restrict__ g, const float* __restrict__ b)
{
    int row = blockIdx.x, tid = threadIdx.x;
    __shared__ float red[256];
    float v[4];
    float s = 0.f;
#pragma unroll
    for (int i = 0; i < 4; i++) { v[i] = tofl(src[(size_t)row * DM + tid + 256 * i]); s += v[i]; }
    red[tid] = s; __syncthreads();
    for (int o = 128; o > 0; o >>= 1) { if (tid < o) red[tid] += red[tid + o]; __syncthreads(); }
    float mean = red[0] * (1.f / DM);
    __syncthreads();
    float vs = 0.f;
#pragma unroll
    for (int i = 0; i < 4; i++) { float dd = v[i] - mean; vs += dd * dd; }
    red[tid] = vs; __syncthreads();
    for (int o = 128; o > 0; o >>= 1) { if (tid < o) red[tid] += red[tid + o]; __syncthreads(); }
    float rstd = rsqrtf(red[0] * (1.f / DM) + 1e-5f);
#pragma unroll
    for (int i = 0; i < 4; i++) {
        int c = tid + 256 * i;
        X[(size_t)row * DM + c] += (v[i] - mean) * rstd * g[c] + b[c];
    }
}

// gate: logits -> softmax max/argmax -> top_idx/top_w + per-expert counts
__global__ __launch_bounds__(64) void gate_kernel(
    const float* __restrict__ X, const float* __restrict__ gw, const float* __restrict__ gb,
    int* __restrict__ top_idx, float* __restrict__ top_w, int* __restrict__ cnt)
{
    int n = blockIdx.x;
    int lane = threadIdx.x;
    float acc[NE] = {};
    for (int k = lane; k < DM; k += 64) {
        float xv = X[(size_t)n * DM + k];
#pragma unroll
        for (int e = 0; e < NE; e++) acc[e] += xv * gw[e * DM + k];
    }
#pragma unroll
    for (int e = 0; e < NE; e++)
        for (int o = 32; o > 0; o >>= 1) acc[e] += __shfl_down(acc[e], o);
    if (lane == 0) {
        float logits[NE];
        float best = -1e30f; int bi = 0;
#pragma unroll
        for (int e = 0; e < NE; e++) {
            logits[e] = acc[e] + gb[e];
            if (logits[e] > best) { best = logits[e]; bi = e; }
        }
        float s = 0.f;
#pragma unroll
        for (int e = 0; e < NE; e++) s += __expf(logits[e] - best);
        top_idx[n] = bi;
        top_w[n] = 1.f / s;
        atomicAdd(&cnt[bi], 1);
    }
}

__global__ void zero8_kernel(int* p) { if (threadIdx.x < 8) p[threadIdx.x] = 0; }

__global__ void offsets_kernel(const int* __restrict__ cnt, int* __restrict__ offs, int* __restrict__ pos)
{
    if (threadIdx.x == 0) {
        int a = 0;
        for (int e = 0; e < NE; e++) { offs[e] = a; a += cnt[e]; pos[e] = 0; }
        offs[NE] = a;
    }
}

__global__ __launch_bounds__(256) void scatter_kernel(
    const int* __restrict__ top_idx, const int* __restrict__ offs,
    int* __restrict__ pos, int* __restrict__ perm)
{
    int n = blockIdx.x * 256 + threadIdx.x;
    if (n >= NTOK) return;
    int e = top_idx[n];
    int slot = atomicAdd(&pos[e], 1);
    perm[offs[e] + slot] = n;
}

__global__ __launch_bounds__(256) void rowmask_kernel(const float* __restrict__ X, float* __restrict__ maskf)
{
    int row = blockIdx.x, tid = threadIdx.x;
    __shared__ float red[256];
    float s = 0.f;
    for (int i = tid; i < DM; i += 256) s += X[(size_t)row * DM + i];
    red[tid] = s; __syncthreads();
    for (int o = 128; o > 0; o >>= 1) { if (tid < o) red[tid] += red[tid + o]; __syncthreads(); }
    if (tid == 0) maskf[row] = (red[0] != 0.f) ? 1.f : 0.f;
}

__global__ __launch_bounds__(256) void cntb_kernel(const float* __restrict__ maskf, float* __restrict__ cntb)
{
    int b = blockIdx.x, tid = threadIdx.x;
    __shared__ float red[256];
    float s = 0.f;
    for (int i = tid; i < LQ; i += 256) s += maskf[b * LQ + i];
    red[tid] = s; __syncthreads();
    for (int o = 128; o > 0; o >>= 1) { if (tid < o) red[tid] += red[tid + o]; __syncthreads(); }
    if (tid == 0) cntb[b] = red[0];
}

__global__ __launch_bounds__(256) void pooled_kernel(
    const float* __restrict__ X, const float* __restrict__ maskf,
    const float* __restrict__ cntb, float* __restrict__ pooled)
{
    int d = blockIdx.x * 256 + threadIdx.x;
    int b = blockIdx.y;
    float s = 0.f;
    for (int l = 0; l < LQ; l++)
        s += X[(size_t)((b << 10) + l) * DM + d] * maskf[(b << 10) + l];
    pooled[b * DM + d] = s / fmaxf(cntb[b], 1.f);
}

__global__ __launch_bounds__(128) void head_kernel(
    const float* __restrict__ pooled,
    const float* __restrict__ fc1w, const float* __restrict__ fc1b,
    const float* __restrict__ fc2w, const float* __restrict__ fc2b,
    float* __restrict__ out)
{
    int b = blockIdx.x;
    int j = threadIdx.x;   // 128
    __shared__ float hbuf[128];
    float acc = fc1b[j];
    for (int k = 0; k < DM; k++) acc += pooled[b * DM + k] * fc1w[j * DM + k];
    hbuf[j] = fmaxf(acc, 0.f);
    __syncthreads();
    if (j < 2) {
        float o = fc2b[j];
        for (int k = 0; k < 128; k++) o += hbuf[k] * fc2w[j * 128 + k];
        out[b * 2 + j] = o;
    }
}

// ---------------------------------------------------------------------------
extern "C" void kernel_launch(void* const* d_in, const int* in_sizes, int n_in,
                              void* d_out, int out_size, void* d_ws, size_t ws_size,
                              hipStream_t stream)
{
    const int*   tokens = (const int*)d_in[0];
    const float* emb    = (const float*)d_in[1];
    const float* pos    = (const float*)d_in[2];
    const float* in_w   = (const float*)d_in[3];
    const float* conv_w = (const float*)d_in[4];
    const float* conv_b = (const float*)d_in[5];
    const float* xp_w   = (const float*)d_in[6];
    const float* dt_w   = (const float*)d_in[7];
    const float* dt_b   = (const float*)d_in[8];
    const float* A_log  = (const float*)d_in[9];
    const float* D_ssm  = (const float*)d_in[10];
    const float* out_w  = (const float*)d_in[11];
    const float* ln1_g  = (const float*)d_in[12];
    const float* ln1_b  = (const float*)d_in[13];
    const float* ln2_g  = (const float*)d_in[14];
    const float* ln2_b  = (const float*)d_in[15];
    const float* gate_w = (const float*)d_in[16];
    const float* gate_b = (const float*)d_in[17];
    const float* e_w1   = (const float*)d_in[18];
    const float* e_b1   = (const float*)d_in[19];
    const float* e_w2   = (const float*)d_in[20];
    const float* e_b2   = (const float*)d_in[21];
    const float* fc1_w  = (const float*)d_in[22];
    const float* fc1_b  = (const float*)d_in[23];
    const float* fc2_w  = (const float*)d_in[24];
    const float* fc2_b  = (const float*)d_in[25];
    float* outp = (float*)d_out;

    // workspace layout (~85 MB peak; MAM/H1 overlay dead XZ region)
    char* wsb = (char*)d_ws;
    size_t off = 0;
    auto alloc = [&](size_t bytes) { char* p = wsb + off; off += (bytes + 255) & ~(size_t)255; return p; };
    float* X    = (float*)alloc((size_t)NTOK * DM * 4);
    bf*   XZ    = (bf*)alloc((size_t)NTOK * 2 * DI * 2);
    bf*   UC    = (bf*)alloc((size_t)NTOK * DI * 2);
    bf*   W96   = (bf*)alloc((size_t)NTOK * 96 * 2);
    bf*   DT    = (bf*)alloc((size_t)NTOK * DI * 2);
    float* top_w  = (float*)alloc(NTOK * 4);
    float* maskf  = (float*)alloc(NTOK * 4);
    float* pooled = (float*)alloc(BB * DM * 4);
    float* cntb   = (float*)alloc(64);
    int* top_idx  = (int*)alloc(NTOK * 4);
    int* perm     = (int*)alloc(NTOK * 4);
    int* cnt      = (int*)alloc(64);
    int* offs     = (int*)alloc(64);
    int* posc     = (int*)alloc(64);
    // overlays (XZ is dead after scan_kernel each layer)
    bf* MAM = XZ;                                  // [NTOK, DM]
    bf* H1  = XZ + (size_t)NTOK * DM;              // [NTOK, HH]

    embed_kernel<<<(NTOK * DM) / 256, 256, 0, stream>>>(tokens, emb, pos, X);

    for (int lay = 0; lay < NLAY; lay++) {
        const float* in_w_l   = in_w   + (size_t)lay * 2 * DI * DM;
        const float* conv_w_l = conv_w + (size_t)lay * DI * DC;
        const float* conv_b_l = conv_b + (size_t)lay * DI;
        const float* xp_w_l   = xp_w   + (size_t)lay * 96 * DI;
        const float* dt_w_l   = dt_w   + (size_t)lay * DI * DTR;
        const float* dt_b_l   = dt_b   + (size_t)lay * DI;
        const float* A_log_l  = A_log  + (size_t)lay * DI * DS;
        const float* D_ssm_l  = D_ssm  + (size_t)lay * DI;
        const float* out_w_l  = out_w  + (size_t)lay * DM * DI;
        const float* gate_w_l = gate_w + (size_t)lay * NE * DM;
        const float* gate_b_l = gate_b + (size_t)lay * NE;
        const float* e_w1_l   = e_w1   + (size_t)lay * NE * HH * DM;
        const float* e_b1_l   = e_b1   + (size_t)lay * NE * HH;
        const float* e_w2_l   = e_w2   + (size_t)lay * NE * DM * HH;
        const float* e_b2_l   = e_b2   + (size_t)lay * NE * DM;

        // in_proj: XZ[4096,4096] = X @ in_w^T
        gemm_nt<float><<<dim3(64, 64, 1), 256, 0, stream>>>(
            X, DM, in_w_l, DM, XZ, 2 * DI, NTOK, 2 * DI, DM,
            nullptr, 0, nullptr, nullptr, nullptr, 0, nullptr, 0, 0);

        // depthwise conv + silu -> UC
        conv_kernel<<<(NTOK * DI) / 256, 256, 0, stream>>>(XZ, conv_w_l, conv_b_l, UC);

        // x_proj: W96[4096,96] = UC @ xp_w^T
        gemm_nt<bf><<<dim3(2, 64, 1), 256, 0, stream>>>(
            UC, DI, xp_w_l, DI, W96, 96, NTOK, 96, DI,
            nullptr, 0, nullptr, nullptr, nullptr, 0, nullptr, 0, 0);

        // dt_proj + softplus: DT[4096,2048] = softplus(W96[:, :64] @ dt_w^T + dt_b)
        gemm_nt<bf><<<dim3(32, 64, 1), 256, 0, stream>>>(
            W96, 96, dt_w_l, DTR, DT, DI, NTOK, DI, DTR,
            dt_b_l, 1, nullptr, nullptr, nullptr, 0, nullptr, 0, 0);

        // SSM scan (+u*D, *silu(z)) -> DT (in place); consumes XZ's z-half
        scan_kernel<<<(BB * DI) / 256, 256, 0, stream>>>(UC, DT, W96, XZ, A_log_l, D_ssm_l);

        // out_proj: MAM[4096,1024] = DT @ out_w^T   (MAM overlays dead XZ)
        gemm_nt<bf><<<dim3(16, 64, 1), 256, 0, stream>>>(
            DT, DI, out_w_l, DI, MAM, DM, NTOK, DM, DI,
            nullptr, 0, nullptr, nullptr, nullptr, 0, nullptr, 0, 0);

        // x += LN1(MAM)
        ln_residual_kernel<<<NTOK, 256, 0, stream>>>(X, MAM, ln1_g + lay * DM, ln1_b + lay * DM);

        // MoE routing
        zero8_kernel<<<1, 32, 0, stream>>>(cnt);
        gate_kernel<<<NTOK, 64, 0, stream>>>(X, gate_w_l, gate_b_l, top_idx, top_w, cnt);
        offsets_kernel<<<1, 1, 0, stream>>>(cnt, offs, posc);
        scatter_kernel<<<NTOK / 256, 256, 0, stream>>>(top_idx, offs, posc, perm);

        // expert GEMM1: H1[perm-order] = relu(X[perm] @ w1[e]^T + b1[e])
        gemm_nt<float><<<dim3(16, 64, NE), 256, 0, stream>>>(
            X, DM, e_w1_l, DM, H1, HH, NTOK, HH, DM,
            e_b1_l, 2, cnt, offs, perm, 1, nullptr,
            (long long)HH * DM, (long long)HH);

        // expert GEMM2: MAM[token] = top_w * (H1 @ w2[e]^T + b2[e])
        gemm_nt<bf><<<dim3(16, 64, NE), 256, 0, stream>>>(
            H1, HH, e_w2_l, HH, MAM, DM, NTOK, DM, HH,
            e_b2_l, 0, cnt, offs, perm, 2, top_w,
            (long long)DM * HH, (long long)DM);

        // x += LN2(MAM)
        ln_residual_kernel<<<NTOK, 256, 0, stream>>>(X, MAM, ln2_g + lay * DM, ln2_b + lay * DM);
    }

    // pooling + head
    rowmask_kernel<<<NTOK, 256, 0, stream>>>(X, maskf);
    cntb_kernel<<<BB, 256, 0, stream>>>(maskf, cntb);
    pooled_kernel<<<dim3(DM / 256, BB, 1), 256, 0, stream>>>(X, maskf, cntb, pooled);
    head_kernel<<<BB, 128, 0, stream>>>(pooled, fc1_w, fc1_b, fc2_w, fc2_b, outp);
}

// Round 3
// 5993.633 us; speedup vs baseline: 1.3345x; 1.3345x over previous
//
#include <hip/hip_runtime.h>
#include <hip/hip_bf16.h>

using bf = __hip_bfloat16;

// Model dims
#define V_   32000
#define DM   1024
#define LQ   1024
#define BB   4
#define NLAY 2
#define NE   8
#define HH   1024
#define DS   16
#define DC   4
#define DI   2048
#define DTR  64
#define NTOK (BB*LQ)   // 4096

// scan chunking
#define NC 8
#define CL (LQ/NC)     // 128

__device__ inline float tofl(float x) { return x; }
__device__ inline float tofl(bf x) { return __bfloat162float(x); }

template<typename T> __device__ inline T fromf(float v);
template<> __device__ inline float fromf<float>(float v) { return v; }
template<> __device__ inline bf fromf<bf>(float v) { return __float2bfloat16(v); }

// ---------------------------------------------------------------------------
// Tiled GEMM: C[M,N] = epi(A[M,K] @ B[N,K]^T + bias), f32 accumulate.
// Template: TA/TC dtypes, TM/TN tile, MR/NR per-thread micro-tile.
// 256 threads; TKK=16. K must be a multiple of 16.
// Expert mode (cnt non-null, grid.z = e): permmode&1 gather A rows via perm;
// permmode&2 scatter C rows via perm, scale by top_w[token].
// ---------------------------------------------------------------------------
template<typename TA, typename TC, int TM, int TN, int MR, int NR>
__global__ __launch_bounds__(256) void gemm_t(
    const TA* __restrict__ A, int lda,
    const float* __restrict__ Bw, int ldb,
    TC* __restrict__ C, int ldc,
    int M, int N, int K,
    const float* __restrict__ bias, int epi,        // 0 none, 1 softplus, 2 relu
    const int* __restrict__ cnt, const int* __restrict__ offs,
    const int* __restrict__ perm, int permmode,
    const float* __restrict__ scale,
    long long strideB_e, long long stride_bias_e)
{
    constexpr int TX = TN / NR;
    constexpr int TY = TM / MR;
    static_assert(TX * TY == 256, "bad tile config");

    int e = blockIdx.z;
    int Meff = M, rowoff = 0;
    if (cnt) {
        Meff = cnt[e];
        rowoff = offs[e];
        Bw += (long long)e * strideB_e;
        if (bias) bias += (long long)e * stride_bias_e;
    }
    int m0 = blockIdx.y * TM;
    if (m0 >= Meff) return;
    int n0 = blockIdx.x * TN;

    __shared__ float As[16][TM];
    __shared__ float Bs[16][TN];

    int tid = threadIdx.x;
    int tx = tid % TX, ty = tid / TX;
    float acc[MR][NR] = {};

    for (int k0 = 0; k0 < K; k0 += 16) {
        for (int i = tid; i < TM * 16; i += 256) {
            int r = i >> 4, c = i & 15;
            int m = m0 + r;
            float v = 0.f;
            if (m < Meff) {
                int ar = rowoff + m;
                int arow = (permmode & 1) ? perm[ar] : ar;
                v = tofl(A[(size_t)arow * lda + k0 + c]);
            }
            As[c][r] = v;
        }
        for (int i = tid; i < TN * 16; i += 256) {
            int r = i >> 4, c = i & 15;
            int n = n0 + r;
            float v = 0.f;
            if (n < N) v = Bw[(size_t)n * ldb + k0 + c];
            Bs[c][r] = v;
        }
        __syncthreads();
#pragma unroll
        for (int kk = 0; kk < 16; ++kk) {
            float av[MR], bv[NR];
#pragma unroll
            for (int i = 0; i < MR; i += 4)
                *(float4*)&av[i] = *(const float4*)&As[kk][ty * MR + i];
#pragma unroll
            for (int j = 0; j < NR; j += 4)
                *(float4*)&bv[j] = *(const float4*)&Bs[kk][tx * NR + j];
#pragma unroll
            for (int i = 0; i < MR; i++)
#pragma unroll
                for (int j = 0; j < NR; j++) acc[i][j] += av[i] * bv[j];
        }
        __syncthreads();
    }

#pragma unroll
    for (int i = 0; i < MR; i++) {
        int m = m0 + ty * MR + i;
        if (m >= Meff) continue;
        long long crow;
        float sc = 1.f;
        int ar = rowoff + m;
        if (permmode & 2) { int tok = perm[ar]; crow = tok; sc = scale[tok]; }
        else crow = ar;
#pragma unroll
        for (int j = 0; j < NR; j++) {
            int n = n0 + tx * NR + j;
            if (n >= N) continue;
            float v = acc[i][j];
            if (bias) v += bias[n];
            if (epi == 1) v = (v > 20.f) ? v : log1pf(__expf(v));
            else if (epi == 2) v = fmaxf(v, 0.f);
            v *= sc;
            C[crow * ldc + n] = fromf<TC>(v);
        }
    }
}

// ---------------------------------------------------------------------------
__global__ __launch_bounds__(256) void embed_kernel(
    const int* __restrict__ tokens, const float* __restrict__ emb,
    const float* __restrict__ pos, float* __restrict__ X)
{
    int id = blockIdx.x * 256 + threadIdx.x;   // NTOK*DM threads
    int r = id >> 10, d = id & 1023;
    int l = r & (LQ - 1);
    int tok = tokens[r];
    X[id] = emb[(size_t)tok * DM + d] + pos[l * DM + d];
}

// causal depthwise conv (DC=4) + SiLU.  u lives in XZ[:, 0:DI], row stride 2*DI
__global__ __launch_bounds__(256) void conv_kernel(
    const bf* __restrict__ XZ, const float* __restrict__ cw,
    const float* __restrict__ cb, bf* __restrict__ UC)
{
    int id = blockIdx.x * 256 + threadIdx.x;   // NTOK*DI threads
    int d = id & (DI - 1);
    int r = id >> 11;
    int l = r & (LQ - 1);
    float acc = cb[d];
#pragma unroll
    for (int j = 0; j < DC; j++) {
        int ll = l - (DC - 1) + j;
        if (ll >= 0)
            acc += tofl(XZ[(size_t)(r - (DC - 1) + j) * (2 * DI) + d]) * cw[d * DC + j];
    }
    float sg = 1.f / (1.f + __expf(-acc));
    UC[id] = __float2bfloat16(acc * sg);
}

// ---------------------------------------------------------------------------
// Chunked parallel scan.
// PHASE 0: per (b,d,chunk) scan from h=0; emit chunk-final h (Hout) and Σdt.
// combine: per (b,d,n) compose chunk-initial states: hin_c = exp(A·S_{c-1})·hin_{c-1}+hout_{c-1}
// PHASE 1: rescan each chunk from Hin, fuse +u*D and *silu(z), write y over DT.
// Exact vs reference up to exp(sum)=prod(exp) f32 rounding.
// ---------------------------------------------------------------------------
template<int PHASE>
__global__ __launch_bounds__(256) void scan_chunk(
    const bf* __restrict__ UC, bf* __restrict__ DT,
    const float* __restrict__ W96, const bf* __restrict__ XZ,
    const float* __restrict__ A_log, const float* __restrict__ D_ssm,
    float* __restrict__ Hout, float* __restrict__ Stot,
    const float* __restrict__ Hin)
{
    int d = blockIdx.x * 256 + threadIdx.x;    // DI/256 blocks in x
    int c = blockIdx.y, b = blockIdx.z;
    float A[DS];
#pragma unroll
    for (int n = 0; n < DS; n++) A[n] = -__expf(A_log[d * DS + n]);
    float Dv = D_ssm[d];
    float h[DS];
    size_t hbase = ((size_t)(b * DI + d) * NC + c) * DS;
    if (PHASE == 0) {
#pragma unroll
        for (int n = 0; n < DS; n++) h[n] = 0.f;
    } else {
#pragma unroll
        for (int n = 0; n < DS; n += 4)
            *(float4*)&h[n] = *(const float4*)&Hin[hbase + n];
    }
    float S = 0.f;

    for (int t = 0; t < CL; t++) {
        int r = (b << 10) + c * CL + t;
        float u = tofl(UC[(size_t)r * DI + d]);
        float dt = tofl(DT[(size_t)r * DI + d]);
        float du = dt * u;
        if (PHASE == 0) S += dt;
        float y = 0.f;
#pragma unroll
        for (int n = 0; n < DS; n++) {
            float Bv = W96[r * 96 + DTR + n];
            h[n] = __expf(dt * A[n]) * h[n] + du * Bv;
            if (PHASE == 1) y += h[n] * W96[r * 96 + DTR + DS + n];
        }
        if (PHASE == 1) {
            float z = tofl(XZ[(size_t)r * (2 * DI) + DI + d]);
            float sil = z / (1.f + __expf(-z));
            DT[(size_t)r * DI + d] = __float2bfloat16((y + u * Dv) * sil);
        }
    }
    if (PHASE == 0) {
#pragma unroll
        for (int n = 0; n < DS; n += 4)
            *(float4*)&Hout[hbase + n] = *(const float4*)&h[n];
        Stot[(size_t)(b * DI + d) * NC + c] = S;
    }
}

__global__ __launch_bounds__(256) void scan_combine(
    const float* __restrict__ Hout, const float* __restrict__ Stot,
    const float* __restrict__ A_log, float* __restrict__ Hin)
{
    int id = blockIdx.x * 256 + threadIdx.x;   // BB*DI*DS = 131072 threads
    int n = id & (DS - 1);
    int d = (id >> 4) & (DI - 1);
    int b = id >> 15;
    float A = -__expf(A_log[d * DS + n]);
    float h = 0.f;
    size_t base = (size_t)(b * DI + d) * NC * DS + n;
    size_t sbase = (size_t)(b * DI + d) * NC;
    for (int c = 0; c < NC; c++) {
        Hin[base + (size_t)c * DS] = h;
        h = __expf(A * Stot[sbase + c]) * h + Hout[base + (size_t)c * DS];
    }
}

// ---------------------------------------------------------------------------
// LN(src) * g + b added into f32 residual stream X.  One block per row.
__global__ __launch_bounds__(256) void ln_residual_kernel(
    float* __restrict__ X, const bf* __restrict__ src,
    const float* __restrict__ g, const float* __restrict__ b)
{
    int row = blockIdx.x, tid = threadIdx.x;
    __shared__ float red[256];
    float v[4];
    float s = 0.f;
#pragma unroll
    for (int i = 0; i < 4; i++) { v[i] = tofl(src[(size_t)row * DM + tid + 256 * i]); s += v[i]; }
    red[tid] = s; __syncthreads();
    for (int o = 128; o > 0; o >>= 1) { if (tid < o) red[tid] += red[tid + o]; __syncthreads(); }
    float mean = red[0] * (1.f / DM);
    __syncthreads();
    float vs = 0.f;
#pragma unroll
    for (int i = 0; i < 4; i++) { float dd = v[i] - mean; vs += dd * dd; }
    red[tid] = vs; __syncthreads();
    for (int o = 128; o > 0; o >>= 1) { if (tid < o) red[tid] += red[tid + o]; __syncthreads(); }
    float rstd = rsqrtf(red[0] * (1.f / DM) + 1e-5f);
#pragma unroll
    for (int i = 0; i < 4; i++) {
        int c = tid + 256 * i;
        X[(size_t)row * DM + c] += (v[i] - mean) * rstd * g[c] + b[c];
    }
}

// gate: logits -> softmax max/argmax -> top_idx/top_w + per-expert counts
__global__ __launch_bounds__(64) void gate_kernel(
    const float* __restrict__ X, const float* __restrict__ gw, const float* __restrict__ gb,
    int* __restrict__ top_idx, float* __restrict__ top_w, int* __restrict__ cnt)
{
    int n = blockIdx.x;
    int lane = threadIdx.x;
    float acc[NE] = {};
    for (int k = lane; k < DM; k += 64) {
        float xv = X[(size_t)n * DM + k];
#pragma unroll
        for (int e = 0; e < NE; e++) acc[e] += xv * gw[e * DM + k];
    }
#pragma unroll
    for (int e = 0; e < NE; e++)
        for (int o = 32; o > 0; o >>= 1) acc[e] += __shfl_down(acc[e], o);
    if (lane == 0) {
        float logits[NE];
        float best = -1e30f; int bi = 0;
#pragma unroll
        for (int e = 0; e < NE; e++) {
            logits[e] = acc[e] + gb[e];
            if (logits[e] > best) { best = logits[e]; bi = e; }
        }
        float s = 0.f;
#pragma unroll
        for (int e = 0; e < NE; e++) s += __expf(logits[e] - best);
        top_idx[n] = bi;
        top_w[n] = 1.f / s;
        atomicAdd(&cnt[bi], 1);
    }
}

__global__ void zero8_kernel(int* p) { if (threadIdx.x < 8) p[threadIdx.x] = 0; }

__global__ void offsets_kernel(const int* __restrict__ cnt, int* __restrict__ offs, int* __restrict__ pos)
{
    if (threadIdx.x == 0) {
        int a = 0;
        for (int e = 0; e < NE; e++) { offs[e] = a; a += cnt[e]; pos[e] = 0; }
        offs[NE] = a;
    }
}

__global__ __launch_bounds__(256) void scatter_kernel(
    const int* __restrict__ top_idx, const int* __restrict__ offs,
    int* __restrict__ pos, int* __restrict__ perm)
{
    int n = blockIdx.x * 256 + threadIdx.x;
    if (n >= NTOK) return;
    int e = top_idx[n];
    int slot = atomicAdd(&pos[e], 1);
    perm[offs[e] + slot] = n;
}

__global__ __launch_bounds__(256) void rowmask_kernel(const float* __restrict__ X, float* __restrict__ maskf)
{
    int row = blockIdx.x, tid = threadIdx.x;
    __shared__ float red[256];
    float s = 0.f;
    for (int i = tid; i < DM; i += 256) s += X[(size_t)row * DM + i];
    red[tid] = s; __syncthreads();
    for (int o = 128; o > 0; o >>= 1) { if (tid < o) red[tid] += red[tid + o]; __syncthreads(); }
    if (tid == 0) maskf[row] = (red[0] != 0.f) ? 1.f : 0.f;
}

__global__ __launch_bounds__(256) void cntb_kernel(const float* __restrict__ maskf, float* __restrict__ cntb)
{
    int b = blockIdx.x, tid = threadIdx.x;
    __shared__ float red[256];
    float s = 0.f;
    for (int i = tid; i < LQ; i += 256) s += maskf[b * LQ + i];
    red[tid] = s; __syncthreads();
    for (int o = 128; o > 0; o >>= 1) { if (tid < o) red[tid] += red[tid + o]; __syncthreads(); }
    if (tid == 0) cntb[b] = red[0];
}

__global__ __launch_bounds__(256) void pooled_kernel(
    const float* __restrict__ X, const float* __restrict__ maskf,
    const float* __restrict__ cntb, float* __restrict__ pooled)
{
    int d = blockIdx.x * 256 + threadIdx.x;
    int b = blockIdx.y;
    float s = 0.f;
    for (int l = 0; l < LQ; l++)
        s += X[(size_t)((b << 10) + l) * DM + d] * maskf[(b << 10) + l];
    pooled[b * DM + d] = s / fmaxf(cntb[b], 1.f);
}

__global__ __launch_bounds__(128) void head_kernel(
    const float* __restrict__ pooled,
    const float* __restrict__ fc1w, const float* __restrict__ fc1b,
    const float* __restrict__ fc2w, const float* __restrict__ fc2b,
    float* __restrict__ out)
{
    int b = blockIdx.x;
    int j = threadIdx.x;   // 128
    __shared__ float hbuf[128];
    float acc = fc1b[j];
    for (int k = 0; k < DM; k++) acc += pooled[b * DM + k] * fc1w[j * DM + k];
    hbuf[j] = fmaxf(acc, 0.f);
    __syncthreads();
    if (j < 2) {
        float o = fc2b[j];
        for (int k = 0; k < 128; k++) o += hbuf[k] * fc2w[j * 128 + k];
        out[b * 2 + j] = o;
    }
}

// ---------------------------------------------------------------------------
extern "C" void kernel_launch(void* const* d_in, const int* in_sizes, int n_in,
                              void* d_out, int out_size, void* d_ws, size_t ws_size,
                              hipStream_t stream)
{
    const int*   tokens = (const int*)d_in[0];
    const float* emb    = (const float*)d_in[1];
    const float* pos    = (const float*)d_in[2];
    const float* in_w   = (const float*)d_in[3];
    const float* conv_w = (const float*)d_in[4];
    const float* conv_b = (const float*)d_in[5];
    const float* xp_w   = (const float*)d_in[6];
    const float* dt_w   = (const float*)d_in[7];
    const float* dt_b   = (const float*)d_in[8];
    const float* A_log  = (const float*)d_in[9];
    const float* D_ssm  = (const float*)d_in[10];
    const float* out_w  = (const float*)d_in[11];
    const float* ln1_g  = (const float*)d_in[12];
    const float* ln1_b  = (const float*)d_in[13];
    const float* ln2_g  = (const float*)d_in[14];
    const float* ln2_b  = (const float*)d_in[15];
    const float* gate_w = (const float*)d_in[16];
    const float* gate_b = (const float*)d_in[17];
    const float* e_w1   = (const float*)d_in[18];
    const float* e_b1   = (const float*)d_in[19];
    const float* e_w2   = (const float*)d_in[20];
    const float* e_b2   = (const float*)d_in[21];
    const float* fc1_w  = (const float*)d_in[22];
    const float* fc1_b  = (const float*)d_in[23];
    const float* fc2_w  = (const float*)d_in[24];
    const float* fc2_b  = (const float*)d_in[25];
    float* outp = (float*)d_out;

    // workspace layout (~94 MB peak; MAM/H1 overlay dead XZ region)
    char* wsb = (char*)d_ws;
    size_t off = 0;
    auto alloc = [&](size_t bytes) { char* p = wsb + off; off += (bytes + 255) & ~(size_t)255; return p; };
    float* X    = (float*)alloc((size_t)NTOK * DM * 4);
    bf*   XZ    = (bf*)alloc((size_t)NTOK * 2 * DI * 2);
    bf*   UC    = (bf*)alloc((size_t)NTOK * DI * 2);
    float* W96  = (float*)alloc((size_t)NTOK * 96 * 4);
    bf*   DT    = (bf*)alloc((size_t)NTOK * DI * 2);
    float* Hout = (float*)alloc((size_t)BB * DI * NC * DS * 4);
    float* Hin  = (float*)alloc((size_t)BB * DI * NC * DS * 4);
    float* Stot = (float*)alloc((size_t)BB * DI * NC * 4);
    float* top_w  = (float*)alloc(NTOK * 4);
    float* maskf  = (float*)alloc(NTOK * 4);
    float* pooled = (float*)alloc(BB * DM * 4);
    float* cntb   = (float*)alloc(64);
    int* top_idx  = (int*)alloc(NTOK * 4);
    int* perm     = (int*)alloc(NTOK * 4);
    int* cnt      = (int*)alloc(64);
    int* offs     = (int*)alloc(64);
    int* posc     = (int*)alloc(64);
    // overlays (XZ is dead after scan phase 1 each layer)
    bf* MAM = XZ;                                  // [NTOK, DM]
    bf* H1  = XZ + (size_t)NTOK * DM;              // [NTOK, HH]

    embed_kernel<<<(NTOK * DM) / 256, 256, 0, stream>>>(tokens, emb, pos, X);

    for (int lay = 0; lay < NLAY; lay++) {
        const float* in_w_l   = in_w   + (size_t)lay * 2 * DI * DM;
        const float* conv_w_l = conv_w + (size_t)lay * DI * DC;
        const float* conv_b_l = conv_b + (size_t)lay * DI;
        const float* xp_w_l   = xp_w   + (size_t)lay * 96 * DI;
        const float* dt_w_l   = dt_w   + (size_t)lay * DI * DTR;
        const float* dt_b_l   = dt_b   + (size_t)lay * DI;
        const float* A_log_l  = A_log  + (size_t)lay * DI * DS;
        const float* D_ssm_l  = D_ssm  + (size_t)lay * DI;
        const float* out_w_l  = out_w  + (size_t)lay * DM * DI;
        const float* gate_w_l = gate_w + (size_t)lay * NE * DM;
        const float* gate_b_l = gate_b + (size_t)lay * NE;
        const float* e_w1_l   = e_w1   + (size_t)lay * NE * HH * DM;
        const float* e_b1_l   = e_b1   + (size_t)lay * NE * HH;
        const float* e_w2_l   = e_w2   + (size_t)lay * NE * DM * HH;
        const float* e_b2_l   = e_b2   + (size_t)lay * NE * DM;

        // in_proj: XZ[4096,4096] = X @ in_w^T   (128x128 tile, 8x8 micro)
        gemm_t<float, bf, 128, 128, 8, 8><<<dim3(32, 32, 1), 256, 0, stream>>>(
            X, DM, in_w_l, DM, XZ, 2 * DI, NTOK, 2 * DI, DM,
            nullptr, 0, nullptr, nullptr, nullptr, 0, nullptr, 0, 0);

        // depthwise conv + silu -> UC
        conv_kernel<<<(NTOK * DI) / 256, 256, 0, stream>>>(XZ, conv_w_l, conv_b_l, UC);

        // x_proj: W96[4096,96] (f32) = UC @ xp_w^T
        gemm_t<bf, float, 64, 64, 4, 4><<<dim3(2, 64, 1), 256, 0, stream>>>(
            UC, DI, xp_w_l, DI, W96, 96, NTOK, 96, DI,
            nullptr, 0, nullptr, nullptr, nullptr, 0, nullptr, 0, 0);

        // dt_proj + softplus: DT[4096,2048] = softplus(W96[:, :64] @ dt_w^T + dt_b)
        gemm_t<float, bf, 128, 64, 8, 4><<<dim3(32, 32, 1), 256, 0, stream>>>(
            W96, 96, dt_w_l, DTR, DT, DI, NTOK, DI, DTR,
            dt_b_l, 1, nullptr, nullptr, nullptr, 0, nullptr, 0, 0);

        // chunked scan: phase0 -> combine -> phase1 (writes gated y over DT)
        scan_chunk<0><<<dim3(DI / 256, NC, BB), 256, 0, stream>>>(
            UC, DT, W96, XZ, A_log_l, D_ssm_l, Hout, Stot, nullptr);
        scan_combine<<<(BB * DI * DS) / 256, 256, 0, stream>>>(Hout, Stot, A_log_l, Hin);
        scan_chunk<1><<<dim3(DI / 256, NC, BB), 256, 0, stream>>>(
            UC, DT, W96, XZ, A_log_l, D_ssm_l, Hout, Stot, Hin);

        // out_proj: MAM[4096,1024] = DT @ out_w^T   (MAM overlays dead XZ)
        gemm_t<bf, bf, 128, 64, 8, 4><<<dim3(16, 32, 1), 256, 0, stream>>>(
            DT, DI, out_w_l, DI, MAM, DM, NTOK, DM, DI,
            nullptr, 0, nullptr, nullptr, nullptr, 0, nullptr, 0, 0);

        // x += LN1(MAM)
        ln_residual_kernel<<<NTOK, 256, 0, stream>>>(X, MAM, ln1_g + lay * DM, ln1_b + lay * DM);

        // MoE routing
        zero8_kernel<<<1, 32, 0, stream>>>(cnt);
        gate_kernel<<<NTOK, 64, 0, stream>>>(X, gate_w_l, gate_b_l, top_idx, top_w, cnt);
        offsets_kernel<<<1, 1, 0, stream>>>(cnt, offs, posc);
        scatter_kernel<<<NTOK / 256, 256, 0, stream>>>(top_idx, offs, posc, perm);

        // expert GEMM1: H1[perm-order] = relu(X[perm] @ w1[e]^T + b1[e])
        gemm_t<float, bf, 128, 64, 8, 4><<<dim3(16, 32, NE), 256, 0, stream>>>(
            X, DM, e_w1_l, DM, H1, HH, NTOK, HH, DM,
            e_b1_l, 2, cnt, offs, perm, 1, nullptr,
            (long long)HH * DM, (long long)HH);

        // expert GEMM2: MAM[token] = top_w * (H1 @ w2[e]^T + b2[e])
        gemm_t<bf, bf, 128, 64, 8, 4><<<dim3(16, 32, NE), 256, 0, stream>>>(
            H1, HH, e_w2_l, HH, MAM, DM, NTOK, DM, HH,
            e_b2_l, 0, cnt, offs, perm, 2, top_w,
            (long long)DM * HH, (long long)DM);

        // x += LN2(MAM)
        ln_residual_kernel<<<NTOK, 256, 0, stream>>>(X, MAM, ln2_g + lay * DM, ln2_b + lay * DM);
    }

    // pooling + head
    rowmask_kernel<<<NTOK, 256, 0, stream>>>(X, maskf);
    cntb_kernel<<<BB, 256, 0, stream>>>(maskf, cntb);
    pooled_kernel<<<dim3(DM / 256, BB, 1), 256, 0, stream>>>(X, maskf, cntb, pooled);
    head_kernel<<<BB, 128, 0, stream>>>(pooled, fc1_w, fc1_b, fc2_w, fc2_b, outp);
}

// Round 5
// 2740.018 us; speedup vs baseline: 2.9192x; 2.1874x over previous
//
#include <hip/hip_runtime.h>
#include <hip/hip_bf16.h>

using bf = __hip_bfloat16;

// Model dims
#define V_   32000
#define DM   1024
#define LQ   1024
#define BB   4
#define NLAY 2
#define NE   8
#define HH   1024
#define DS   16
#define DC   4
#define DI   2048
#define DTR  64
#define NTOK (BB*LQ)   // 4096

// scan chunking
#define NC 8
#define CL (LQ/NC)     // 128

typedef __attribute__((ext_vector_type(8))) short s8v;
typedef __attribute__((ext_vector_type(4))) float f4v;

__device__ inline float tofl(float x) { return x; }
__device__ inline float tofl(bf x) { return __bfloat162float(x); }

template<typename T> __device__ inline T fromf(float v);
template<> __device__ inline float fromf<float>(float v) { return v; }
template<> __device__ inline bf fromf<bf>(float v) { return __float2bfloat16(v); }

__device__ inline unsigned short f2bfu(float x) {
    bf h = __float2bfloat16(x);
    return __builtin_bit_cast(unsigned short, h);
}
__device__ inline float bfu2f(unsigned short u) {
    bf h = __builtin_bit_cast(bf, u);
    return __bfloat162float(h);
}

__device__ inline f4v mfma16(s8v a, s8v b, f4v c) {
    return __builtin_amdgcn_mfma_f32_16x16x32_bf16(a, b, c, 0, 0, 0);
}

// ---------------------------------------------------------------------------
// MFMA GEMM: C[M,N] = epi(A[M,K] @ B[N,K]^T + bias), f32 accumulate in AGPRs.
// 128x128 workgroup tile, BK=32, 4 waves each computing 64x64 via 4x4 frags
// of v_mfma_f32_16x16x32_bf16.
// Precision: split each f32 operand into hi=bf16(x), lo=bf16(x-hi);
// accumulate Ahi*Bhi + Ahi*Blo (+ Alo*Bhi if SPLITA) -> ~2^-17 rel vs f32.
// SPLITA=0 only for A already stored bf16 (lo==0 exactly).
// Expert mode (cnt non-null, grid.z = e): permmode&1 gather A rows via perm;
// permmode&2 scatter C rows via perm and scale by scale[token].
// K must be a multiple of 32. M,N arbitrary (zero-pad staging, guarded store).
// ---------------------------------------------------------------------------
template<typename TA, typename TC, int SPLITA, int SPLITB>
__global__ __launch_bounds__(256) void gemm_mfma(
    const TA* __restrict__ A, int lda,
    const float* __restrict__ Bw, int ldb,
    TC* __restrict__ C, int ldc,
    int M, int N, int K,
    const float* __restrict__ bias, int epi,        // 0 none, 1 softplus, 2 relu
    const int* __restrict__ cnt, const int* __restrict__ offs,
    const int* __restrict__ perm, int permmode,
    const float* __restrict__ scale,
    long long strideB_e, long long stride_bias_e)
{
    int e = blockIdx.z;
    int Meff = M, rowoff = 0;
    if (cnt) {
        Meff = cnt[e];
        rowoff = offs[e];
        Bw += (long long)e * strideB_e;
        if (bias) bias += (long long)e * stride_bias_e;
    }
    int m0 = blockIdx.y * 128;
    if (m0 >= Meff) return;
    int n0 = blockIdx.x * 128;

    // LDS tiles, row stride padded to 40 shorts (80B) -> 2-way bank access (free)
    __shared__ __align__(16) unsigned short Ah[128][40];
    __shared__ __align__(16) unsigned short Al[SPLITA ? 128 : 1][SPLITA ? 40 : 8];
    __shared__ __align__(16) unsigned short Bh[128][40];
    __shared__ __align__(16) unsigned short Bl[SPLITB ? 128 : 1][SPLITB ? 40 : 8];

    int t = threadIdx.x;
    int lane = t & 63;
    int wv = t >> 6;                       // wave 0..3
    int wm = (wv & 1) * 64, wn = (wv >> 1) * 64;
    int fr = lane & 15, kq = lane >> 4;    // fragment row, k-quad

    f4v acc[4][4];
#pragma unroll
    for (int i = 0; i < 4; i++)
#pragma unroll
        for (int j = 0; j < 4; j++) acc[i][j] = 0.f;

    // staging coords: thread covers row (t>>1), 16-col half ((t&1)*16)
    int sr = t >> 1, scb = (t & 1) << 4;

    // A row index (with optional gather), computed once
    int arow = -1;
    {
        int m = m0 + sr;
        if (m < Meff) { int ar = rowoff + m; arow = (permmode & 1) ? perm[ar] : ar; }
    }
    int brow = (n0 + sr < N) ? (n0 + sr) : -1;

    for (int k0 = 0; k0 < K; k0 += 32) {
        // ---- stage A tile (128 x 32) ----
        if constexpr (sizeof(TA) == 4) {
#pragma unroll
            for (int i = 0; i < 16; i += 4) {
                float4 v = {0.f, 0.f, 0.f, 0.f};
                if (arow >= 0) v = *(const float4*)((const float*)A + (size_t)arow * lda + k0 + scb + i);
                ushort4 hh;
                hh.x = f2bfu(v.x); hh.y = f2bfu(v.y); hh.z = f2bfu(v.z); hh.w = f2bfu(v.w);
                *(ushort4*)&Ah[sr][scb + i] = hh;
                if constexpr (SPLITA) {
                    ushort4 ll;
                    ll.x = f2bfu(v.x - bfu2f(hh.x));
                    ll.y = f2bfu(v.y - bfu2f(hh.y));
                    ll.z = f2bfu(v.z - bfu2f(hh.z));
                    ll.w = f2bfu(v.w - bfu2f(hh.w));
                    *(ushort4*)&Al[sr][scb + i] = ll;
                }
            }
        } else {
#pragma unroll
            for (int i = 0; i < 16; i += 8) {
                ushort4 u0 = {0,0,0,0}, u1 = {0,0,0,0};
                if (arow >= 0) {
                    const ushort4* p = (const ushort4*)((const unsigned short*)A + (size_t)arow * lda + k0 + scb + i);
                    u0 = p[0]; u1 = p[1];
                }
                *(ushort4*)&Ah[sr][scb + i] = u0;
                *(ushort4*)&Ah[sr][scb + i + 4] = u1;
            }
        }
        // ---- stage B tile (128 x 32), always f32 weights ----
#pragma unroll
        for (int i = 0; i < 16; i += 4) {
            float4 v = {0.f, 0.f, 0.f, 0.f};
            if (brow >= 0) v = *(const float4*)(Bw + (size_t)brow * ldb + k0 + scb + i);
            ushort4 hh;
            hh.x = f2bfu(v.x); hh.y = f2bfu(v.y); hh.z = f2bfu(v.z); hh.w = f2bfu(v.w);
            *(ushort4*)&Bh[sr][scb + i] = hh;
            if constexpr (SPLITB) {
                ushort4 ll;
                ll.x = f2bfu(v.x - bfu2f(hh.x));
                ll.y = f2bfu(v.y - bfu2f(hh.y));
                ll.z = f2bfu(v.z - bfu2f(hh.z));
                ll.w = f2bfu(v.w - bfu2f(hh.w));
                *(ushort4*)&Bl[sr][scb + i] = ll;
            }
        }
        __syncthreads();

        // ---- fragments + MFMA ----
        s8v ah[4], bh[4], al[4], bl[4];
#pragma unroll
        for (int mi = 0; mi < 4; mi++) ah[mi] = *(const s8v*)&Ah[wm + mi * 16 + fr][kq * 8];
#pragma unroll
        for (int ni = 0; ni < 4; ni++) bh[ni] = *(const s8v*)&Bh[wn + ni * 16 + fr][kq * 8];
        if constexpr (SPLITA) {
#pragma unroll
            for (int mi = 0; mi < 4; mi++) al[mi] = *(const s8v*)&Al[wm + mi * 16 + fr][kq * 8];
        }
        if constexpr (SPLITB) {
#pragma unroll
            for (int ni = 0; ni < 4; ni++) bl[ni] = *(const s8v*)&Bl[wn + ni * 16 + fr][kq * 8];
        }
#pragma unroll
        for (int mi = 0; mi < 4; mi++)
#pragma unroll
            for (int ni = 0; ni < 4; ni++) {
                acc[mi][ni] = mfma16(ah[mi], bh[ni], acc[mi][ni]);
                if constexpr (SPLITB) acc[mi][ni] = mfma16(ah[mi], bl[ni], acc[mi][ni]);
                if constexpr (SPLITA) acc[mi][ni] = mfma16(al[mi], bh[ni], acc[mi][ni]);
            }
        __syncthreads();
    }

    // ---- epilogue: C row = (lane>>4)*4 + reg, col = lane&15 ----
#pragma unroll
    for (int mi = 0; mi < 4; mi++) {
#pragma unroll
        for (int r4 = 0; r4 < 4; r4++) {
            int m = m0 + wm + mi * 16 + kq * 4 + r4;
            if (m >= Meff) continue;
            long long crow;
            float sc = 1.f;
            int ar = rowoff + m;
            if (permmode & 2) { int tok = perm[ar]; crow = tok; sc = scale[tok]; }
            else crow = ar;
#pragma unroll
            for (int ni = 0; ni < 4; ni++) {
                int n = n0 + wn + ni * 16 + fr;
                if (n >= N) continue;
                float v = acc[mi][ni][r4];
                if (bias) v += bias[n];
                if (epi == 1) v = (v > 20.f) ? v : log1pf(__expf(v));
                else if (epi == 2) v = fmaxf(v, 0.f);
                v *= sc;
                C[crow * ldc + n] = fromf<TC>(v);
            }
        }
    }
}

// ---------------------------------------------------------------------------
__global__ __launch_bounds__(256) void embed_kernel(
    const int* __restrict__ tokens, const float* __restrict__ emb,
    const float* __restrict__ pos, float* __restrict__ X)
{
    int id = blockIdx.x * 256 + threadIdx.x;   // NTOK*DM threads
    int r = id >> 10, d = id & 1023;
    int l = r & (LQ - 1);
    int tok = tokens[r];
    X[id] = emb[(size_t)tok * DM + d] + pos[l * DM + d];
}

// causal depthwise conv (DC=4) + SiLU.  u lives in XZ[:, 0:DI], row stride 2*DI
__global__ __launch_bounds__(256) void conv_kernel(
    const bf* __restrict__ XZ, const float* __restrict__ cw,
    const float* __restrict__ cb, bf* __restrict__ UC)
{
    int id = blockIdx.x * 256 + threadIdx.x;   // NTOK*DI threads
    int d = id & (DI - 1);
    int r = id >> 11;
    int l = r & (LQ - 1);
    float acc = cb[d];
#pragma unroll
    for (int j = 0; j < DC; j++) {
        int ll = l - (DC - 1) + j;
        if (ll >= 0)
            acc += tofl(XZ[(size_t)(r - (DC - 1) + j) * (2 * DI) + d]) * cw[d * DC + j];
    }
    float sg = 1.f / (1.f + __expf(-acc));
    UC[id] = __float2bfloat16(acc * sg);
}

// ---------------------------------------------------------------------------
// Chunked parallel scan. PHASE 0: scan chunks from h=0, emit chunk-final h +
// sum(dt). combine: compose chunk-initial states. PHASE 1: rescan from Hin,
// fuse +u*D and *silu(z), write y (f32) over DT in place.
// ---------------------------------------------------------------------------
template<int PHASE>
__global__ __launch_bounds__(256) void scan_chunk(
    const bf* __restrict__ UC, float* __restrict__ DT,
    const float* __restrict__ W96, const bf* __restrict__ XZ,
    const float* __restrict__ A_log, const float* __restrict__ D_ssm,
    float* __restrict__ Hout, float* __restrict__ Stot,
    const float* __restrict__ Hin)
{
    int d = blockIdx.x * 256 + threadIdx.x;    // DI/256 blocks in x
    int c = blockIdx.y, b = blockIdx.z;
    float A[DS];
#pragma unroll
    for (int n = 0; n < DS; n++) A[n] = -__expf(A_log[d * DS + n]);
    float Dv = D_ssm[d];
    float h[DS];
    size_t hbase = ((size_t)(b * DI + d) * NC + c) * DS;
    if (PHASE == 0) {
#pragma unroll
        for (int n = 0; n < DS; n++) h[n] = 0.f;
    } else {
#pragma unroll
        for (int n = 0; n < DS; n += 4)
            *(float4*)&h[n] = *(const float4*)&Hin[hbase + n];
    }
    float S = 0.f;

    for (int t = 0; t < CL; t++) {
        int r = (b << 10) + c * CL + t;
        float u = tofl(UC[(size_t)r * DI + d]);
        float dt = DT[(size_t)r * DI + d];
        float du = dt * u;
        if (PHASE == 0) S += dt;
        float y = 0.f;
#pragma unroll
        for (int n = 0; n < DS; n++) {
            float Bv = W96[r * 96 + DTR + n];
            h[n] = __expf(dt * A[n]) * h[n] + du * Bv;
            if (PHASE == 1) y += h[n] * W96[r * 96 + DTR + DS + n];
        }
        if (PHASE == 1) {
            float z = tofl(XZ[(size_t)r * (2 * DI) + DI + d]);
            float sil = z / (1.f + __expf(-z));
            DT[(size_t)r * DI + d] = (y + u * Dv) * sil;
        }
    }
    if (PHASE == 0) {
#pragma unroll
        for (int n = 0; n < DS; n += 4)
            *(float4*)&Hout[hbase + n] = *(const float4*)&h[n];
        Stot[(size_t)(b * DI + d) * NC + c] = S;
    }
}

__global__ __launch_bounds__(256) void scan_combine(
    const float* __restrict__ Hout, const float* __restrict__ Stot,
    const float* __restrict__ A_log, float* __restrict__ Hin)
{
    int id = blockIdx.x * 256 + threadIdx.x;   // BB*DI*DS = 131072 threads
    int n = id & (DS - 1);
    int d = (id >> 4) & (DI - 1);
    int b = id >> 15;
    float A = -__expf(A_log[d * DS + n]);
    float h = 0.f;
    size_t base = (size_t)(b * DI + d) * NC * DS + n;
    size_t sbase = (size_t)(b * DI + d) * NC;
    for (int c = 0; c < NC; c++) {
        Hin[base + (size_t)c * DS] = h;
        h = __expf(A * Stot[sbase + c]) * h + Hout[base + (size_t)c * DS];
    }
}

// ---------------------------------------------------------------------------
// LN(src) * g + b added into f32 residual stream X.  One block per row.
__global__ __launch_bounds__(256) void ln_residual_kernel(
    float* __restrict__ X, const float* __restrict__ src,
    const float* __restrict__ g, const float* __restrict__ b)
{
    int row = blockIdx.x, tid = threadIdx.x;
    __shared__ float red[256];
    float v[4];
    float s = 0.f;
#pragma unroll
    for (int i = 0; i < 4; i++) { v[i] = src[(size_t)row * DM + tid + 256 * i]; s += v[i]; }
    red[tid] = s; __syncthreads();
    for (int o = 128; o > 0; o >>= 1) { if (tid < o) red[tid] += red[tid + o]; __syncthreads(); }
    float mean = red[0] * (1.f / DM);
    __syncthreads();
    float vs = 0.f;
#pragma unroll
    for (int i = 0; i < 4; i++) { float dd = v[i] - mean; vs += dd * dd; }
    red[tid] = vs; __syncthreads();
    for (int o = 128; o > 0; o >>= 1) { if (tid < o) red[tid] += red[tid + o]; __syncthreads(); }
    float rstd = rsqrtf(red[0] * (1.f / DM) + 1e-5f);
#pragma unroll
    for (int i = 0; i < 4; i++) {
        int c = tid + 256 * i;
        X[(size_t)row * DM + c] += (v[i] - mean) * rstd * g[c] + b[c];
    }
}

// gate: logits -> softmax max/argmax -> top_idx/top_w + per-expert counts
__global__ __launch_bounds__(64) void gate_kernel(
    const float* __restrict__ X, const float* __restrict__ gw, const float* __restrict__ gb,
    int* __restrict__ top_idx, float* __restrict__ top_w, int* __restrict__ cnt)
{
    int n = blockIdx.x;
    int lane = threadIdx.x;
    float acc[NE] = {};
    for (int k = lane; k < DM; k += 64) {
        float xv = X[(size_t)n * DM + k];
#pragma unroll
        for (int e = 0; e < NE; e++) acc[e] += xv * gw[e * DM + k];
    }
#pragma unroll
    for (int e = 0; e < NE; e++)
        for (int o = 32; o > 0; o >>= 1) acc[e] += __shfl_down(acc[e], o);
    if (lane == 0) {
        float logits[NE];
        float best = -1e30f; int bi = 0;
#pragma unroll
        for (int e = 0; e < NE; e++) {
            logits[e] = acc[e] + gb[e];
            if (logits[e] > best) { best = logits[e]; bi = e; }
        }
        float s = 0.f;
#pragma unroll
        for (int e = 0; e < NE; e++) s += __expf(logits[e] - best);
        top_idx[n] = bi;
        top_w[n] = 1.f / s;
        atomicAdd(&cnt[bi], 1);
    }
}

__global__ void zero8_kernel(int* p) { if (threadIdx.x < 8) p[threadIdx.x] = 0; }

__global__ void offsets_kernel(const int* __restrict__ cnt, int* __restrict__ offs, int* __restrict__ pos)
{
    if (threadIdx.x == 0) {
        int a = 0;
        for (int e = 0; e < NE; e++) { offs[e] = a; a += cnt[e]; pos[e] = 0; }
        offs[NE] = a;
    }
}

__global__ __launch_bounds__(256) void scatter_kernel(
    const int* __restrict__ top_idx, const int* __restrict__ offs,
    int* __restrict__ pos, int* __restrict__ perm)
{
    int n = blockIdx.x * 256 + threadIdx.x;
    if (n >= NTOK) return;
    int e = top_idx[n];
    int slot = atomicAdd(&pos[e], 1);
    perm[offs[e] + slot] = n;
}

__global__ __launch_bounds__(256) void rowmask_kernel(const float* __restrict__ X, float* __restrict__ maskf)
{
    int row = blockIdx.x, tid = threadIdx.x;
    __shared__ float red[256];
    float s = 0.f;
    for (int i = tid; i < DM; i += 256) s += X[(size_t)row * DM + i];
    red[tid] = s; __syncthreads();
    for (int o = 128; o > 0; o >>= 1) { if (tid < o) red[tid] += red[tid + o]; __syncthreads(); }
    if (tid == 0) maskf[row] = (red[0] != 0.f) ? 1.f : 0.f;
}

__global__ __launch_bounds__(256) void cntb_kernel(const float* __restrict__ maskf, float* __restrict__ cntb)
{
    int b = blockIdx.x, tid = threadIdx.x;
    __shared__ float red[256];
    float s = 0.f;
    for (int i = tid; i < LQ; i += 256) s += maskf[b * LQ + i];
    red[tid] = s; __syncthreads();
    for (int o = 128; o > 0; o >>= 1) { if (tid < o) red[tid] += red[tid + o]; __syncthreads(); }
    if (tid == 0) cntb[b] = red[0];
}

__global__ __launch_bounds__(256) void pooled_kernel(
    const float* __restrict__ X, const float* __restrict__ maskf,
    const float* __restrict__ cntb, float* __restrict__ pooled)
{
    int d = blockIdx.x * 256 + threadIdx.x;
    int b = blockIdx.y;
    float s = 0.f;
    for (int l = 0; l < LQ; l++)
        s += X[(size_t)((b << 10) + l) * DM + d] * maskf[(b << 10) + l];
    pooled[b * DM + d] = s / fmaxf(cntb[b], 1.f);
}

__global__ __launch_bounds__(128) void head_kernel(
    const float* __restrict__ pooled,
    const float* __restrict__ fc1w, const float* __restrict__ fc1b,
    const float* __restrict__ fc2w, const float* __restrict__ fc2b,
    float* __restrict__ out)
{
    int b = blockIdx.x;
    int j = threadIdx.x;   // 128
    __shared__ float hbuf[128];
    float acc = fc1b[j];
    for (int k = 0; k < DM; k++) acc += pooled[b * DM + k] * fc1w[j * DM + k];
    hbuf[j] = fmaxf(acc, 0.f);
    __syncthreads();
    if (j < 2) {
        float o = fc2b[j];
        for (int k = 0; k < 128; k++) o += hbuf[k] * fc2w[j * 128 + k];
        out[b * 2 + j] = o;
    }
}

// ---------------------------------------------------------------------------
extern "C" void kernel_launch(void* const* d_in, const int* in_sizes, int n_in,
                              void* d_out, int out_size, void* d_ws, size_t ws_size,
                              hipStream_t stream)
{
    const int*   tokens = (const int*)d_in[0];
    const float* emb    = (const float*)d_in[1];
    const float* pos    = (const float*)d_in[2];
    const float* in_w   = (const float*)d_in[3];
    const float* conv_w = (const float*)d_in[4];
    const float* conv_b = (const float*)d_in[5];
    const float* xp_w   = (const float*)d_in[6];
    const float* dt_w   = (const float*)d_in[7];
    const float* dt_b   = (const float*)d_in[8];
    const float* A_log  = (const float*)d_in[9];
    const float* D_ssm  = (const float*)d_in[10];
    const float* out_w  = (const float*)d_in[11];
    const float* ln1_g  = (const float*)d_in[12];
    const float* ln1_b  = (const float*)d_in[13];
    const float* ln2_g  = (const float*)d_in[14];
    const float* ln2_b  = (const float*)d_in[15];
    const float* gate_w = (const float*)d_in[16];
    const float* gate_b = (const float*)d_in[17];
    const float* e_w1   = (const float*)d_in[18];
    const float* e_b1   = (const float*)d_in[19];
    const float* e_w2   = (const float*)d_in[20];
    const float* e_b2   = (const float*)d_in[21];
    const float* fc1_w  = (const float*)d_in[22];
    const float* fc1_b  = (const float*)d_in[23];
    const float* fc2_w  = (const float*)d_in[24];
    const float* fc2_b  = (const float*)d_in[25];
    float* outp = (float*)d_out;

    // workspace layout (~111 MB peak; MAM/H1 f32 overlay dead XZ region)
    char* wsb = (char*)d_ws;
    size_t off = 0;
    auto alloc = [&](size_t bytes) { char* p = wsb + off; off += (bytes + 255) & ~(size_t)255; return p; };
    float* X    = (float*)alloc((size_t)NTOK * DM * 4);
    char* xzraw = (char*)alloc((size_t)NTOK * 2 * DI * 2);
    bf*   XZ    = (bf*)xzraw;
    bf*   UC    = (bf*)alloc((size_t)NTOK * DI * 2);
    float* W96  = (float*)alloc((size_t)NTOK * 96 * 4);
    float* DT   = (float*)alloc((size_t)NTOK * DI * 4);
    float* Hout = (float*)alloc((size_t)BB * DI * NC * DS * 4);
    float* Hin  = (float*)alloc((size_t)BB * DI * NC * DS * 4);
    float* Stot = (float*)alloc((size_t)BB * DI * NC * 4);
    float* top_w  = (float*)alloc(NTOK * 4);
    float* maskf  = (float*)alloc(NTOK * 4);
    float* pooled = (float*)alloc(BB * DM * 4);
    float* cntb   = (float*)alloc(64);
    int* top_idx  = (int*)alloc(NTOK * 4);
    int* perm     = (int*)alloc(NTOK * 4);
    int* cnt      = (int*)alloc(64);
    int* offs     = (int*)alloc(64);
    int* posc     = (int*)alloc(64);
    // overlays (XZ dead after scan phase 1): MAM f32 16MB + H1 f32 16MB = 32MB
    float* MAM = (float*)xzraw;                              // [NTOK, DM] f32
    float* H1  = (float*)(xzraw + (size_t)NTOK * DM * 4);    // [NTOK, HH] f32

    embed_kernel<<<(NTOK * DM) / 256, 256, 0, stream>>>(tokens, emb, pos, X);

    for (int lay = 0; lay < NLAY; lay++) {
        const float* in_w_l   = in_w   + (size_t)lay * 2 * DI * DM;
        const float* conv_w_l = conv_w + (size_t)lay * DI * DC;
        const float* conv_b_l = conv_b + (size_t)lay * DI;
        const float* xp_w_l   = xp_w   + (size_t)lay * 96 * DI;
        const float* dt_w_l   = dt_w   + (size_t)lay * DI * DTR;
        const float* dt_b_l   = dt_b   + (size_t)lay * DI;
        const float* A_log_l  = A_log  + (size_t)lay * DI * DS;
        const float* D_ssm_l  = D_ssm  + (size_t)lay * DI;
        const float* out_w_l  = out_w  + (size_t)lay * DM * DI;
        const float* gate_w_l = gate_w + (size_t)lay * NE * DM;
        const float* gate_b_l = gate_b + (size_t)lay * NE;
        const float* e_w1_l   = e_w1   + (size_t)lay * NE * HH * DM;
        const float* e_b1_l   = e_b1   + (size_t)lay * NE * HH;
        const float* e_w2_l   = e_w2   + (size_t)lay * NE * DM * HH;
        const float* e_b2_l   = e_b2   + (size_t)lay * NE * DM;

        // in_proj: XZ[4096,4096] = X @ in_w^T  (split A f32 + split B)
        gemm_mfma<float, bf, 1, 1><<<dim3(32, 32, 1), 256, 0, stream>>>(
            X, DM, in_w_l, DM, XZ, 2 * DI, NTOK, 2 * DI, DM,
            nullptr, 0, nullptr, nullptr, nullptr, 0, nullptr, 0, 0);

        // depthwise conv + silu -> UC
        conv_kernel<<<(NTOK * DI) / 256, 256, 0, stream>>>(XZ, conv_w_l, conv_b_l, UC);

        // x_proj: W96[4096,96] (f32) = UC @ xp_w^T  (A bf16 stored)
        gemm_mfma<bf, float, 0, 1><<<dim3(1, 32, 1), 256, 0, stream>>>(
            UC, DI, xp_w_l, DI, W96, 96, NTOK, 96, DI,
            nullptr, 0, nullptr, nullptr, nullptr, 0, nullptr, 0, 0);

        // dt_proj + softplus: DT (f32) = softplus(W96[:, :64] @ dt_w^T + dt_b)
        gemm_mfma<float, float, 1, 1><<<dim3(16, 32, 1), 256, 0, stream>>>(
            W96, 96, dt_w_l, DTR, DT, DI, NTOK, DI, DTR,
            dt_b_l, 1, nullptr, nullptr, nullptr, 0, nullptr, 0, 0);

        // chunked scan: phase0 -> combine -> phase1 (writes gated y f32 over DT)
        scan_chunk<0><<<dim3(DI / 256, NC, BB), 256, 0, stream>>>(
            UC, DT, W96, XZ, A_log_l, D_ssm_l, Hout, Stot, nullptr);
        scan_combine<<<(BB * DI * DS) / 256, 256, 0, stream>>>(Hout, Stot, A_log_l, Hin);
        scan_chunk<1><<<dim3(DI / 256, NC, BB), 256, 0, stream>>>(
            UC, DT, W96, XZ, A_log_l, D_ssm_l, Hout, Stot, Hin);

        // out_proj: MAM[4096,1024] (f32) = DT @ out_w^T  (MAM overlays dead XZ)
        gemm_mfma<float, float, 1, 1><<<dim3(8, 32, 1), 256, 0, stream>>>(
            DT, DI, out_w_l, DI, MAM, DM, NTOK, DM, DI,
            nullptr, 0, nullptr, nullptr, nullptr, 0, nullptr, 0, 0);

        // x += LN1(MAM)
        ln_residual_kernel<<<NTOK, 256, 0, stream>>>(X, MAM, ln1_g + lay * DM, ln1_b + lay * DM);

        // MoE routing
        zero8_kernel<<<1, 32, 0, stream>>>(cnt);
        gate_kernel<<<NTOK, 64, 0, stream>>>(X, gate_w_l, gate_b_l, top_idx, top_w, cnt);
        offsets_kernel<<<1, 1, 0, stream>>>(cnt, offs, posc);
        scatter_kernel<<<NTOK / 256, 256, 0, stream>>>(top_idx, offs, posc, perm);

        // expert GEMM1: H1 (f32) = relu(X[perm] @ w1[e]^T + b1[e])
        gemm_mfma<float, float, 1, 1><<<dim3(8, 32, NE), 256, 0, stream>>>(
            X, DM, e_w1_l, DM, H1, HH, NTOK, HH, DM,
            e_b1_l, 2, cnt, offs, perm, 1, nullptr,
            (long long)HH * DM, (long long)HH);

        // expert GEMM2: MAM[token] (f32) = top_w * (H1 @ w2[e]^T + b2[e])
        gemm_mfma<float, float, 1, 1><<<dim3(8, 32, NE), 256, 0, stream>>>(
            H1, HH, e_w2_l, HH, MAM, DM, NTOK, DM, HH,
            e_b2_l, 0, cnt, offs, perm, 2, top_w,
            (long long)DM * HH, (long long)DM);

        // x += LN2(MAM)
        ln_residual_kernel<<<NTOK, 256, 0, stream>>>(X, MAM, ln2_g + lay * DM, ln2_b + lay * DM);
    }

    // pooling + head
    rowmask_kernel<<<NTOK, 256, 0, stream>>>(X, maskf);
    cntb_kernel<<<BB, 256, 0, stream>>>(maskf, cntb);
    pooled_kernel<<<dim3(DM / 256, BB, 1), 256, 0, stream>>>(X, maskf, cntb, pooled);
    head_kernel<<<BB, 128, 0, stream>>>(pooled, fc1_w, fc1_b, fc2_w, fc2_b, outp);
}